// Round 11
// baseline (154.214 us; speedup 1.0000x reference)
//
#include <hip/hip_runtime.h>

#define N_NODES 50000
#define DIM     64
#define HEADS   4
#define NEDGES  400000
#define HD      256   // HEADS*DIM
#define MAXDEG  32    // realized max degree (multinomial 400K->50K) ~ 24-27
#define NPREP   2048  // k_prep grid: 8 blocks/CU (R8 config; cohort filter reverted)
#define ZSTRIDE 264   // halves per LDS zn row (528B: +4-bank phase per row)

// v_dot2_f32_f16 packed dot-product (verified passing rounds 1-10).
#define USE_DOT2 1

typedef _Float16 half2v __attribute__((ext_vector_type(2)));
typedef _Float16 half4v __attribute__((ext_vector_type(4)));
typedef _Float16 half8v __attribute__((ext_vector_type(8)));
typedef float    f32x4  __attribute__((ext_vector_type(4)));

union EU { int2 i2; half4v h; };
union HU { unsigned int u; half2v h; };

__device__ __forceinline__ half2v h2cast(unsigned int u) { HU c; c.u = u; return c.h; }

#if USE_DOT2
#define DOT2(a, b, c) __builtin_amdgcn_fdot2((a), (b), (c), false)
#else
__device__ __forceinline__ float DOT2(half2v a, half2v b, float c) {
    return fmaf((float)a[1], (float)b[1], fmaf((float)a[0], (float)b[0], c));
}
#endif

// ---------------------------------------------------------------------------
// Kernel 0 (k_prep). R11: x16 (fp16, 6.4MB) replaced by x8 (int8 per-node-
// scaled, 3.2MB) + xscale (fp16/node, 100KB). Rationale: R0-R10 established
// both kernels run at ~1TB/s scattered-line throughput; time == bytes. The
// gather table at 6.4MB thrashes per-XCD L2 (4MB); at 3.2MB it mostly fits.
// Scatter reverted to plain R8 form (R10 cohort filter: traffic moved, time
// didn't, net +2us from the 8x rescan).
// NOTE (round 14): hipLaunchCooperativeKernel silently no-ops under this
// harness's graph capture — do NOT merge these into a cooperative kernel.
// ---------------------------------------------------------------------------
__global__ __launch_bounds__(256) void k_prep(
    const float* __restrict__ x,
    const float* __restrict__ W_lin,
    const float* __restrict__ attn_src,
    const float* __restrict__ attn_dst,
    const float* __restrict__ W_out,
    const int* __restrict__ ei,
    _Float16* __restrict__ G2T,        // [64][256]
    signed char* __restrict__ x8,      // [N][64] int8, per-node scaled
    _Float16* __restrict__ xscale,     // [N] dequant scale = rowmax/127
    float* __restrict__ S,
    int* __restrict__ cnt,
    unsigned short* __restrict__ bucketJ)
{
    __shared__ float weffsh[8][68];    // +4 pad: conflict-free combo rows
    const int b = blockIdx.x, t = threadIdx.x;
    const int base = b * 32;           // this block's node chunk

    const size_t e0 = (size_t)base * DIM + (size_t)t * 8;
    const bool do_x = (e0 + 8 <= (size_t)N_NODES * DIM);
    float4 u = {0.f, 0.f, 0.f, 0.f}, v = {0.f, 0.f, 0.f, 0.f};
    if (do_x) {
        u = *(const float4*)(x + e0);
        v = *(const float4*)(x + e0 + 4);
    }

    // edge j-scatter (plain R8 form)
    for (int e = b * 256 + t; e < NEDGES; e += NPREP * 256) {
        const int i = ei[e];
        const int j = ei[NEDGES + e];
        const int slot = atomicAdd(&cnt[i], 1);
        if (slot < MAXDEG)
            bucketJ[(size_t)i * MAXDEG + slot] = (unsigned short)j;
    }

    // per-block weff into LDS (4-way split chains)
    for (int id = t; id < 512; id += 256) {
        const int sd = id >> 8, rem = id & 255, h = rem >> 6, k = rem & 63;
        const float* av = sd ? attn_dst : attn_src;
        float a0 = 0.f, a1 = 0.f, a2 = 0.f, a3 = 0.f;
#pragma unroll
        for (int d = 0; d < DIM; d += 4) {
            a0 = fmaf(av[h * DIM + d],     W_lin[(h * DIM + d)     * DIM + k], a0);
            a1 = fmaf(av[h * DIM + d + 1], W_lin[(h * DIM + d + 1) * DIM + k], a1);
            a2 = fmaf(av[h * DIM + d + 2], W_lin[(h * DIM + d + 2) * DIM + k], a2);
            a3 = fmaf(av[h * DIM + d + 3], W_lin[(h * DIM + d + 3) * DIM + k], a3);
        }
        weffsh[sd * 4 + h][k] = (a0 + a1) + (a2 + a3);
    }

    // G2T slice (blocks 0..63), 4-way split chains
    {
        const int id = b * 256 + t;
        if (id < 64 * 256) {
            const int d = id >> 8, rem = id & 255, m = rem >> 2, h = rem & 3;
            float a0 = 0.f, a1 = 0.f, a2 = 0.f, a3 = 0.f;
#pragma unroll
            for (int k = 0; k < DIM; k += 4) {
                a0 = fmaf(W_lin[(h * DIM + k)     * DIM + m], W_out[d * HD + h * DIM + k],     a0);
                a1 = fmaf(W_lin[(h * DIM + k + 1) * DIM + m], W_out[d * HD + h * DIM + k + 1], a1);
                a2 = fmaf(W_lin[(h * DIM + k + 2) * DIM + m], W_out[d * HD + h * DIM + k + 2], a2);
                a3 = fmaf(W_lin[(h * DIM + k + 3) * DIM + m], W_out[d * HD + h * DIM + k + 3], a3);
            }
            G2T[d * HD + m * 4 + h] = (_Float16)((a0 + a1) + (a2 + a3));
        }
    }
    __syncthreads();

    // S (single chunk per block; 4-way split chains) + int8 quantize
    {
        const int ni = base + (t >> 3);
        if (ni < N_NODES) {
            const int combo = t & 7;
            const float4* xr = (const float4*)(x + (size_t)ni * DIM);
            const float4* wr = (const float4*)(weffsh[combo]);
            float a0 = 0.f, a1 = 0.f, a2 = 0.f, a3 = 0.f;
#pragma unroll
            for (int kp = 0; kp < 16; kp += 4) {
                const float4 xa = xr[kp],     wa = wr[kp];
                const float4 xb = xr[kp + 1], wb = wr[kp + 1];
                const float4 xc = xr[kp + 2], wc = wr[kp + 2];
                const float4 xd = xr[kp + 3], wd = wr[kp + 3];
                a0 = fmaf(xa.x, wa.x, a0); a0 = fmaf(xa.y, wa.y, a0);
                a0 = fmaf(xa.z, wa.z, a0); a0 = fmaf(xa.w, wa.w, a0);
                a1 = fmaf(xb.x, wb.x, a1); a1 = fmaf(xb.y, wb.y, a1);
                a1 = fmaf(xb.z, wb.z, a1); a1 = fmaf(xb.w, wb.w, a1);
                a2 = fmaf(xc.x, wc.x, a2); a2 = fmaf(xc.y, wc.y, a2);
                a2 = fmaf(xc.z, wc.z, a2); a2 = fmaf(xc.w, wc.w, a2);
                a3 = fmaf(xd.x, wd.x, a3); a3 = fmaf(xd.y, wd.y, a3);
                a3 = fmaf(xd.z, wd.z, a3); a3 = fmaf(xd.w, wd.w, a3);
            }
            S[(size_t)ni * 8 + combo] = (a0 + a1) + (a2 + a3);
        }
        if (do_x) {
            // row max over the 8-thread group sharing this node's row
            float m0 = fabsf(u.x);
            m0 = fmaxf(m0, fabsf(u.y)); m0 = fmaxf(m0, fabsf(u.z)); m0 = fmaxf(m0, fabsf(u.w));
            m0 = fmaxf(m0, fabsf(v.x)); m0 = fmaxf(m0, fabsf(v.y)); m0 = fmaxf(m0, fabsf(v.z)); m0 = fmaxf(m0, fabsf(v.w));
            m0 = fmaxf(m0, __shfl_xor(m0, 1, 64));
            m0 = fmaxf(m0, __shfl_xor(m0, 2, 64));
            m0 = fmaxf(m0, __shfl_xor(m0, 4, 64));
            const float inv = m0 > 0.f ? 127.f / m0 : 0.f;
            const int q0 = (int)rintf(u.x * inv), q1 = (int)rintf(u.y * inv);
            const int q2 = (int)rintf(u.z * inv), q3 = (int)rintf(u.w * inv);
            const int q4 = (int)rintf(v.x * inv), q5 = (int)rintf(v.y * inv);
            const int q6 = (int)rintf(v.z * inv), q7 = (int)rintf(v.w * inv);
            uint2 pk;
            pk.x = (q0 & 255) | ((q1 & 255) << 8) | ((q2 & 255) << 16) | ((unsigned)q3 << 24);
            pk.y = (q4 & 255) | ((q5 & 255) << 8) | ((q6 & 255) << 16) | ((unsigned)q7 << 24);
            *(uint2*)(x8 + e0) = pk;
            if ((t & 7) == 0)
                xscale[base + (t >> 3)] = (_Float16)(m0 * (1.f / 127.f));
        }
    }
}

// ---------------------------------------------------------------------------
// Kernel 1 (k_ga). R11 changes vs R8:
//   - gathers int8 x8 rows (64B/row; per-XCD L2-resident) instead of fp16
//     x16 (128B/row, L2-thrash).
//   - per-edge scale s_j folded into the 4 exp weights at SETUP (e' = e*s_j);
//     inner loop unchanged except u16 load + int8->f16 unpack.
//   - softmax denominator moved to SETUP (raw-e butterfly over 32 slot
//     lanes -> dsh LDS); dd dots and its combine removed from the loop.
//   - residual read from exact fp32 x (dense, cached).
// ---------------------------------------------------------------------------
__global__ __launch_bounds__(256) void k_ga(
    const int* __restrict__ cnt,
    const unsigned short* __restrict__ bucketJ,
    const float* __restrict__ S,
    const signed char* __restrict__ x8,
    const _Float16* __restrict__ xscale,
    const float* __restrict__ x,
    const _Float16* __restrict__ G2T,
    const float* __restrict__ b_out,
    const float* __restrict__ ln_g,
    const float* __restrict__ ln_b,
    float* __restrict__ out)
{
    __shared__ _Float16 znsh[16 * ZSTRIDE];   // 8448 B
    __shared__ float ysh[16][68];             // 4352 B (stride 68: 16B-aligned rows)
    __shared__ int2  esh[16 * 32];            // 4096 B: masked scaled-exp pairs
    __shared__ float dsh[16][4];              // 256 B: per-node per-head denominators

    const int t = threadIdx.x, wv = t >> 6, l = t & 63;
    const int n0 = blockIdx.x * 16;
    const int side = l >> 5, p = l & 31;

    // ---- setup: independent loads first ----
    const int4 degv = *(const int4*)(cnt + n0 + wv * 4);

    int Jr[4];
#pragma unroll
    for (int r = 0; r < 4; ++r)
        Jr[r] = bucketJ[(unsigned)(n0 + wv * 4 + r) * MAXDEG + p];

    float4 SDr[4];
#pragma unroll
    for (int r = 0; r < 4; ++r)
        SDr[r] = *(const float4*)(S + (unsigned)(n0 + wv * 4 + r) * 8 + 4); // dst (no dep)

    int degc[4];
    degc[0] = degv.x < MAXDEG ? degv.x : MAXDEG;
    degc[1] = degv.y < MAXDEG ? degv.y : MAXDEG;
    degc[2] = degv.z < MAXDEG ? degv.z : MAXDEG;
    degc[3] = degv.w < MAXDEG ? degv.w : MAXDEG;

#pragma unroll
    for (int r = 0; r < 4; ++r)
        Jr[r] = (p < degc[r]) ? Jr[r] : 0;    // mask poison slots BEFORE gather

    float4 SSr[4];
#pragma unroll
    for (int r = 0; r < 4; ++r)
        SSr[r] = *(const float4*)(S + (unsigned)Jr[r] * 8);               // src part

    float SCr[4];
#pragma unroll
    for (int r = 0; r < 4; ++r)
        SCr[r] = (float)xscale[Jr[r]];                                    // dequant scale

#pragma unroll
    for (int r = 0; r < 4; ++r) {
        float u2;
        u2 = SDr[r].x + SSr[r].x; u2 = u2 > 0.f ? u2 : 0.2f * u2; float e0 = __expf(u2);
        u2 = SDr[r].y + SSr[r].y; u2 = u2 > 0.f ? u2 : 0.2f * u2; float e1 = __expf(u2);
        u2 = SDr[r].z + SSr[r].z; u2 = u2 > 0.f ? u2 : 0.2f * u2; float e2 = __expf(u2);
        u2 = SDr[r].w + SSr[r].w; u2 = u2 > 0.f ? u2 : 0.2f * u2; float e3 = __expf(u2);
        if (p >= degc[r]) { e0 = 0.f; e1 = 0.f; e2 = 0.f; e3 = 0.f; }

        // denominator per head: butterfly over the 32 slot lanes (raw e)
        float d0 = e0, d1 = e1, d2 = e2, d3 = e3;
#pragma unroll
        for (int m = 1; m < 32; m <<= 1) {
            d0 += __shfl_xor(d0, m, 64);
            d1 += __shfl_xor(d1, m, 64);
            d2 += __shfl_xor(d2, m, 64);
            d3 += __shfl_xor(d3, m, 64);
        }
        if (l == 0) {
            dsh[wv * 4 + r][0] = d0; dsh[wv * 4 + r][1] = d1;
            dsh[wv * 4 + r][2] = d2; dsh[wv * 4 + r][3] = d3;
        }

        // scale-folded pack (masked slots already zero)
        const float sc = SCr[r];
        EU pk;
        pk.h[0] = (_Float16)(e0 * sc); pk.h[1] = (_Float16)(e1 * sc);
        pk.h[2] = (_Float16)(e2 * sc); pk.h[3] = (_Float16)(e3 * sc);
        if (side == 0) esh[(wv * 4 + r) * 32 + p] = pk.i2;
    }
    __builtin_amdgcn_wave_barrier();   // same-wave DS is in-order; pin compiler order

    // ---- Phase A: pipelined gather, 4 nodes per wave ----
    struct Grp { unsigned short xq[4]; int2 ee[4]; };
    float za[4], zb[4];

    auto stage_group = [&](int r, int s, Grp& g) {
        const int jb = s + side;
#pragma unroll
        for (int q = 0; q < 4; ++q) {
            const int jv = __shfl(Jr[r], jb + 2 * q, 64);
            g.xq[q] = *(const unsigned short*)(x8 + (unsigned)jv * DIM + (p << 1));
        }
        const int eb = (wv * 4 + r) * 32 + jb;
#pragma unroll
        for (int q = 0; q < 4; ++q)
            g.ee[q] = esh[eb + 2 * q];
    };

    auto consume_group = [&](const Grp& g) {
#pragma unroll
        for (int pp = 0; pp < 2; ++pp) {
            const int2 ea = g.ee[2 * pp], eb2 = g.ee[2 * pp + 1];
            const unsigned E0 = __builtin_amdgcn_perm(eb2.x, ea.x, 0x05040100u);
            const unsigned E1 = __builtin_amdgcn_perm(eb2.x, ea.x, 0x07060302u);
            const unsigned E2 = __builtin_amdgcn_perm(eb2.y, ea.y, 0x05040100u);
            const unsigned E3 = __builtin_amdgcn_perm(eb2.y, ea.y, 0x07060302u);
            const int ua = g.xq[2 * pp], ub = g.xq[2 * pp + 1];
            const float fa0 = (float)(signed char)(ua & 255);
            const float fa1 = (float)(signed char)(ua >> 8);
            const float fb0 = (float)(signed char)(ub & 255);
            const float fb1 = (float)(signed char)(ub >> 8);
            half2v va, vb;
            va[0] = (_Float16)fa0; va[1] = (_Float16)fb0;   // channel 2p: {A,B}
            vb[0] = (_Float16)fa1; vb[1] = (_Float16)fb1;   // channel 2p+1
            const half2v f0 = h2cast(E0), f1 = h2cast(E1);
            const half2v f2 = h2cast(E2), f3 = h2cast(E3);
            za[0] = DOT2(f0, va, za[0]); za[1] = DOT2(f1, va, za[1]);
            za[2] = DOT2(f2, va, za[2]); za[3] = DOT2(f3, va, za[3]);
            zb[0] = DOT2(f0, vb, zb[0]); zb[1] = DOT2(f1, vb, zb[1]);
            zb[2] = DOT2(f2, vb, zb[2]); zb[3] = DOT2(f3, vb, zb[3]);
        }
    };

    Grp cur, nxt, remb;
    stage_group(0, 0, cur);

#pragma unroll
    for (int r = 0; r < 4; ++r) {
        const bool rem = degc[r] > 8;                  // wave-uniform branch
        if (rem) stage_group(r, 8, remb);              // hide remainder latency
        if (r < 3) stage_group(r + 1, 0, nxt);         // prefetch next node

#pragma unroll
        for (int h = 0; h < 4; ++h) { za[h] = 0.f; zb[h] = 0.f; }

        consume_group(cur);
        if (rem) {
            consume_group(remb);
            for (int s = 16; s < degc[r]; s += 8) {    // deg>16: ~1% of nodes
                Grp tg;
                stage_group(r, s, tg);
                consume_group(tg);
            }
        }

        // combine the two edge-halves
#pragma unroll
        for (int h = 0; h < 4; ++h) {
            za[h] += __shfl_xor(za[h], 32, 64);
            zb[h] += __shfl_xor(zb[h], 32, 64);
        }
        if (side == 0) {
            const float4 dv = *(const float4*)(dsh[wv * 4 + r]);
            const float r0 = __builtin_amdgcn_rcpf(dv.x + 1e-9f);
            const float r1 = __builtin_amdgcn_rcpf(dv.y + 1e-9f);
            const float r2 = __builtin_amdgcn_rcpf(dv.z + 1e-9f);
            const float r3 = __builtin_amdgcn_rcpf(dv.w + 1e-9f);
            half8v o;
            o[0] = (_Float16)(za[0] * r0); o[1] = (_Float16)(za[1] * r1);
            o[2] = (_Float16)(za[2] * r2); o[3] = (_Float16)(za[3] * r3);
            o[4] = (_Float16)(zb[0] * r0); o[5] = (_Float16)(zb[1] * r1);
            o[6] = (_Float16)(zb[2] * r2); o[7] = (_Float16)(zb[3] * r3);
            *(half8v*)(znsh + (wv * 4 + r) * ZSTRIDE + p * 8) = o;
        }
        cur = nxt;
    }
    __syncthreads();

    // ---- Phase B: MFMA col-tile wv; 2 independent 4-chains ----
    const int mrow = l & 15, quad = l >> 4;
    half8v A[8];
    const _Float16* zr = znsh + mrow * ZSTRIDE + quad * 8;
#pragma unroll
    for (int s = 0; s < 8; ++s)
        A[s] = *(const half8v*)(zr + 32 * s);

    const _Float16* gp = G2T + (size_t)(wv * 16 + mrow) * HD + quad * 8;
    f32x4 c0 = {0.f, 0.f, 0.f, 0.f}, c1 = {0.f, 0.f, 0.f, 0.f};
#pragma unroll
    for (int s = 0; s < 4; ++s)
        c0 = __builtin_amdgcn_mfma_f32_16x16x32_f16(A[s], *(const half8v*)(gp + 32 * s), c0, 0, 0, 0);
#pragma unroll
    for (int s = 4; s < 8; ++s)
        c1 = __builtin_amdgcn_mfma_f32_16x16x32_f16(A[s], *(const half8v*)(gp + 32 * s), c1, 0, 0, 0);
    const f32x4 c = c0 + c1;

    const int col = wv * 16 + mrow;
    const float bo = b_out[col];
#pragma unroll
    for (int rho = 0; rho < 4; ++rho) {
        const int nl = quad * 4 + rho;
        const float o = c[rho] + bo;
        const float eo = o > 0.f ? o : expm1f(o);       // ELU(alpha=1)
        ysh[nl][col] = eo + x[(size_t)(n0 + nl) * DIM + col];   // exact fp32 residual
    }
    __syncthreads();

    // ---- epilogue: node-PARALLEL LN; 16-lane group g owns node wv*4+g ----
    {
        const int g = l >> 4, c4 = (l & 15) * 4;
        const int nl = wv * 4 + g;
        const float4 yv = *(const float4*)(&ysh[nl][c4]);
        float s1 = (yv.x + yv.y) + (yv.z + yv.w);
        float s2 = fmaf(yv.x, yv.x, fmaf(yv.y, yv.y, fmaf(yv.z, yv.z, yv.w * yv.w)));
#pragma unroll
        for (int off = 8; off > 0; off >>= 1) {
            s1 += __shfl_xor(s1, off, 64);
            s2 += __shfl_xor(s2, off, 64);
        }
        const float mu = s1 * (1.f / 64.f);
        const float var = fmaf(-mu, mu, s2 * (1.f / 64.f));
        const float rr = rsqrtf(var + 1e-5f);
        const float4 gv = *(const float4*)(ln_g + c4);
        const float4 bv = *(const float4*)(ln_b + c4);
        float4 ov;
        ov.x = (yv.x - mu) * rr * gv.x + bv.x;
        ov.y = (yv.y - mu) * rr * gv.y + bv.y;
        ov.z = (yv.z - mu) * rr * gv.z + bv.z;
        ov.w = (yv.w - mu) * rr * gv.w + bv.w;
        *(float4*)(out + (size_t)(n0 + nl) * DIM + c4) = ov;
    }
}

// ---------------------------------------------------------------------------
extern "C" void kernel_launch(void* const* d_in, const int* in_sizes, int n_in,
                              void* d_out, int out_size, void* d_ws, size_t ws_size,
                              hipStream_t stream)
{
    const float* x        = (const float*)d_in[0];
    const int*   ei       = (const int*)d_in[1];
    const float* W_lin    = (const float*)d_in[2];
    const float* attn_src = (const float*)d_in[3];
    const float* attn_dst = (const float*)d_in[4];
    const float* W_out    = (const float*)d_in[5];
    const float* b_out    = (const float*)d_in[6];
    const float* ln_g     = (const float*)d_in[7];
    const float* ln_b     = (const float*)d_in[8];
    float* out = (float*)d_out;

    // Workspace (~8.3 MB used; harness poisons full alloc regardless):
    //   x8 3.2MB | xscale 100KB | S 1.6MB | G2T 32KB | cnt 0.2MB | bucketJ 3.2MB
    char* ws = (char*)d_ws;
    signed char*    x8     = (signed char*)ws;
    _Float16*       xscale = (_Float16*)(x8 + (size_t)N_NODES * DIM);
    float*          S      = (float*)(xscale + N_NODES);
    _Float16*       G2T    = (_Float16*)(S + (size_t)N_NODES * 8);
    int*            cnt    = (int*)(G2T + 64 * HD);
    unsigned short* bucketJ= (unsigned short*)(cnt + N_NODES);

    hipMemsetAsync(cnt, 0, (size_t)N_NODES * sizeof(int), stream);

    k_prep<<<NPREP, 256, 0, stream>>>(x, W_lin, attn_src, attn_dst, W_out, ei,
                                      G2T, x8, xscale, S, cnt, bucketJ);

    k_ga<<<N_NODES / 16, 256, 0, stream>>>(cnt, bucketJ, S, x8, xscale, x, G2T,
                                           b_out, ln_g, ln_b, out);
}

// Round 12
// 146.344 us; speedup vs baseline: 1.0538x; 1.0538x over previous
//
#include <hip/hip_runtime.h>

#define N_NODES 50000
#define DIM     64
#define HEADS   4
#define NEDGES  400000
#define HD      256   // HEADS*DIM
#define MAXDEG  32    // realized max degree (multinomial 400K->50K) ~ 24-27
#define NPREP   2048  // k_prep grid: 8 blocks/CU (R5 best-measured config)
#define ZSTRIDE 264   // halves per LDS zn row (528B: +4-bank phase per row)

// v_dot2_f32_f16 packed dot-product (verified passing rounds 1-11, absmax 0.03125).
#define USE_DOT2 1

// ---------------------------------------------------------------------------
// R12: REVERT to the best-measured configuration (R5, 146.6us) after the
// R9 diagnostic + R10/R11 probes closed the case:
//   - k_prep is scatter-bound: 35.5us of 64B-line-granular random writebacks
//     at ~660GB/s (measured by 4x-amplified diag, R9). EIGHT interventions
//     (occupancy x8, LDS conflicts->0, chain split, atomic line-padding,
//     XCD-cohort ownership, u16/int8 payloads, phase split) all null —
//     time == touched-lines / scattered-line-throughput.
//   - k_ga is the same wall from the gather side (~43us; VALU halved with
//     zero time change, R0->R3).
//   - Structural floor: fill 45 (harness) + k_prep 44 + k_ga 42 + gaps 12
//     ~= 143-147us. R5 measured 146.6 — at the floor.
// ---------------------------------------------------------------------------

typedef _Float16 half2v __attribute__((ext_vector_type(2)));
typedef _Float16 half4v __attribute__((ext_vector_type(4)));
typedef _Float16 half8v __attribute__((ext_vector_type(8)));
typedef float    f32x4  __attribute__((ext_vector_type(4)));

union EU { int2 i2; half4v h; };
union HU { unsigned int u; half2v h; };

__device__ __forceinline__ half2v h2cast(unsigned int u) { HU c; c.u = u; return c.h; }

#if USE_DOT2
#define DOT2(a, b, c) __builtin_amdgcn_fdot2((a), (b), (c), false)
#else
__device__ __forceinline__ float DOT2(half2v a, half2v b, float c) {
    return fmaf((float)a[1], (float)b[1], fmaf((float)a[0], (float)b[0], c));
}
#endif

// ---------------------------------------------------------------------------
// Kernel 0 (k_prep): R5 version verbatim. weff + G2T + S + x16 + j-scatter.
// NOTE (round 14): hipLaunchCooperativeKernel silently no-ops under this
// harness's graph capture — do NOT merge these into a cooperative kernel.
// ---------------------------------------------------------------------------
__global__ __launch_bounds__(256) void k_prep(
    const float* __restrict__ x,
    const float* __restrict__ W_lin,
    const float* __restrict__ attn_src,
    const float* __restrict__ attn_dst,
    const float* __restrict__ W_out,
    const int* __restrict__ ei,
    _Float16* __restrict__ G2T,        // [64][256]
    _Float16* __restrict__ x16,
    float* __restrict__ S,
    int* __restrict__ cnt,
    int* __restrict__ bucketJ)
{
    __shared__ float weffsh[8][68];    // +4 pad: conflict-free combo rows
    const int b = blockIdx.x, t = threadIdx.x;
    const int base = b * 32;           // this block's node chunk

    // hoisted x16 source loads (no dependencies; fly under everything below)
    const size_t e0 = (size_t)base * DIM + (size_t)t * 8;
    const bool do_x = (e0 + 8 <= (size_t)N_NODES * DIM);
    float4 u = {0.f, 0.f, 0.f, 0.f}, v = {0.f, 0.f, 0.f, 0.f};
    if (do_x) {
        u = *(const float4*)(x + e0);
        v = *(const float4*)(x + e0 + 4);
    }

    // edge j-scatter (<=1 edge/thread at NPREP=2048)
    for (int e = b * 256 + t; e < NEDGES; e += NPREP * 256) {
        const int i = ei[e];
        const int j = ei[NEDGES + e];
        const int slot = atomicAdd(&cnt[i], 1);
        if (slot < MAXDEG) bucketJ[(size_t)i * MAXDEG + slot] = j;
    }

    // per-block weff into LDS (4-way split chains)
    for (int id = t; id < 512; id += 256) {
        const int sd = id >> 8, rem = id & 255, h = rem >> 6, k = rem & 63;
        const float* av = sd ? attn_dst : attn_src;
        float a0 = 0.f, a1 = 0.f, a2 = 0.f, a3 = 0.f;
#pragma unroll
        for (int d = 0; d < DIM; d += 4) {
            a0 = fmaf(av[h * DIM + d],     W_lin[(h * DIM + d)     * DIM + k], a0);
            a1 = fmaf(av[h * DIM + d + 1], W_lin[(h * DIM + d + 1) * DIM + k], a1);
            a2 = fmaf(av[h * DIM + d + 2], W_lin[(h * DIM + d + 2) * DIM + k], a2);
            a3 = fmaf(av[h * DIM + d + 3], W_lin[(h * DIM + d + 3) * DIM + k], a3);
        }
        weffsh[sd * 4 + h][k] = (a0 + a1) + (a2 + a3);
    }

    // G2T slice (blocks 0..63), 4-way split chains
    {
        const int id = b * 256 + t;
        if (id < 64 * 256) {
            const int d = id >> 8, rem = id & 255, m = rem >> 2, h = rem & 3;
            float a0 = 0.f, a1 = 0.f, a2 = 0.f, a3 = 0.f;
#pragma unroll
            for (int k = 0; k < DIM; k += 4) {
                a0 = fmaf(W_lin[(h * DIM + k)     * DIM + m], W_out[d * HD + h * DIM + k],     a0);
                a1 = fmaf(W_lin[(h * DIM + k + 1) * DIM + m], W_out[d * HD + h * DIM + k + 1], a1);
                a2 = fmaf(W_lin[(h * DIM + k + 2) * DIM + m], W_out[d * HD + h * DIM + k + 2], a2);
                a3 = fmaf(W_lin[(h * DIM + k + 3) * DIM + m], W_out[d * HD + h * DIM + k + 3], a3);
            }
            G2T[d * HD + m * 4 + h] = (_Float16)((a0 + a1) + (a2 + a3));
        }
    }
    __syncthreads();

    // S (single chunk per block; 4-way split chains) + x16 cast
    {
        const int ni = base + (t >> 3);
        if (ni < N_NODES) {
            const int combo = t & 7;
            const float4* xr = (const float4*)(x + (size_t)ni * DIM);
            const float4* wr = (const float4*)(weffsh[combo]);
            float a0 = 0.f, a1 = 0.f, a2 = 0.f, a3 = 0.f;
#pragma unroll
            for (int kp = 0; kp < 16; kp += 4) {
                const float4 xa = xr[kp],     wa = wr[kp];
                const float4 xb = xr[kp + 1], wb = wr[kp + 1];
                const float4 xc = xr[kp + 2], wc = wr[kp + 2];
                const float4 xd = xr[kp + 3], wd = wr[kp + 3];
                a0 = fmaf(xa.x, wa.x, a0); a0 = fmaf(xa.y, wa.y, a0);
                a0 = fmaf(xa.z, wa.z, a0); a0 = fmaf(xa.w, wa.w, a0);
                a1 = fmaf(xb.x, wb.x, a1); a1 = fmaf(xb.y, wb.y, a1);
                a1 = fmaf(xb.z, wb.z, a1); a1 = fmaf(xb.w, wb.w, a1);
                a2 = fmaf(xc.x, wc.x, a2); a2 = fmaf(xc.y, wc.y, a2);
                a2 = fmaf(xc.z, wc.z, a2); a2 = fmaf(xc.w, wc.w, a2);
                a3 = fmaf(xd.x, wd.x, a3); a3 = fmaf(xd.y, wd.y, a3);
                a3 = fmaf(xd.z, wd.z, a3); a3 = fmaf(xd.w, wd.w, a3);
            }
            S[(size_t)ni * 8 + combo] = (a0 + a1) + (a2 + a3);
        }
        if (do_x) {
            half8v hv;
            hv[0]=(_Float16)u.x; hv[1]=(_Float16)u.y; hv[2]=(_Float16)u.z; hv[3]=(_Float16)u.w;
            hv[4]=(_Float16)v.x; hv[5]=(_Float16)v.y; hv[6]=(_Float16)v.z; hv[7]=(_Float16)v.w;
            *(half8v*)(x16 + e0) = hv;
        }
    }
}

// ---------------------------------------------------------------------------
// Kernel 1 (k_ga): R4/R5 version verbatim (best-measured). Setup reorder +
// esh/fdot2 Phase A + split MFMA chains + node-parallel LN epilogue.
// ---------------------------------------------------------------------------
__global__ __launch_bounds__(256) void k_ga(
    const int* __restrict__ cnt,
    const int* __restrict__ bucketJ,
    const float* __restrict__ S,
    const _Float16* __restrict__ x16,
    const _Float16* __restrict__ G2T,
    const float* __restrict__ b_out,
    const float* __restrict__ ln_g,
    const float* __restrict__ ln_b,
    float* __restrict__ out)
{
    __shared__ _Float16 znsh[16 * ZSTRIDE];   // 8448 B
    __shared__ float ysh[16][68];             // 4352 B (stride 68: 16B-aligned rows)
    __shared__ int2  esh[16 * 32];            // 4096 B: masked exp pairs per (node,slot)

    const int t = threadIdx.x, wv = t >> 6, l = t & 63;
    const int n0 = blockIdx.x * 16;
    const int side = l >> 5, p = l & 31;

    // ---- setup: independent loads first ----
    const int4 degv = *(const int4*)(cnt + n0 + wv * 4);

    int Jr[4];
#pragma unroll
    for (int r = 0; r < 4; ++r)
        Jr[r] = bucketJ[(unsigned)(n0 + wv * 4 + r) * MAXDEG + p];

    float4 SDr[4];
#pragma unroll
    for (int r = 0; r < 4; ++r)
        SDr[r] = *(const float4*)(S + (unsigned)(n0 + wv * 4 + r) * 8 + 4); // dst (no dep)

    int degc[4];
    degc[0] = degv.x < MAXDEG ? degv.x : MAXDEG;
    degc[1] = degv.y < MAXDEG ? degv.y : MAXDEG;
    degc[2] = degv.z < MAXDEG ? degv.z : MAXDEG;
    degc[3] = degv.w < MAXDEG ? degv.w : MAXDEG;

#pragma unroll
    for (int r = 0; r < 4; ++r)
        Jr[r] = (p < degc[r]) ? Jr[r] : 0;    // mask poison slots BEFORE gather

    float4 SSr[4];
#pragma unroll
    for (int r = 0; r < 4; ++r)
        SSr[r] = *(const float4*)(S + (unsigned)Jr[r] * 8);               // src part

#pragma unroll
    for (int r = 0; r < 4; ++r) {
        float u;
        u = SDr[r].x + SSr[r].x; u = u > 0.f ? u : 0.2f * u; const float e0 = __expf(u);
        u = SDr[r].y + SSr[r].y; u = u > 0.f ? u : 0.2f * u; const float e1 = __expf(u);
        u = SDr[r].z + SSr[r].z; u = u > 0.f ? u : 0.2f * u; const float e2 = __expf(u);
        u = SDr[r].w + SSr[r].w; u = u > 0.f ? u : 0.2f * u; const float e3 = __expf(u);
        EU pk;
        pk.h[0] = (_Float16)e0; pk.h[1] = (_Float16)e1;
        pk.h[2] = (_Float16)e2; pk.h[3] = (_Float16)e3;
        int2 ev = pk.i2;
        if (p >= degc[r]) { ev.x = 0; ev.y = 0; }   // masked slots contribute 0
        if (side == 0) esh[(wv * 4 + r) * 32 + p] = ev;
    }
    __builtin_amdgcn_wave_barrier();   // same-wave DS is in-order; pin compiler order

    // ---- Phase A: pipelined gather, 4 nodes per wave ----
    struct Grp { half2v xv[4]; int2 ee[4]; };
    float za[4], zb[4], dd[4];
    const half2v one2 = h2cast(0x3C003C00u);   // {1.0h, 1.0h}

    auto stage_group = [&](int r, int s, Grp& g) {
        const int jb = s + side;
#pragma unroll
        for (int q = 0; q < 4; ++q) {
            const int jv = __shfl(Jr[r], jb + 2 * q, 64);
            g.xv[q] = *(const half2v*)(x16 + (unsigned)jv * DIM + (p << 1));
        }
        const int eb = (wv * 4 + r) * 32 + jb;
#pragma unroll
        for (int q = 0; q < 4; ++q)
            g.ee[q] = esh[eb + 2 * q];
    };

    auto consume_group = [&](const Grp& g) {
#pragma unroll
        for (int pp = 0; pp < 2; ++pp) {
            const int2 ea = g.ee[2 * pp], eb2 = g.ee[2 * pp + 1];
            HU xa, xb; xa.h = g.xv[2 * pp]; xb.h = g.xv[2 * pp + 1];
            const unsigned E0 = __builtin_amdgcn_perm(eb2.x, ea.x, 0x05040100u);
            const unsigned E1 = __builtin_amdgcn_perm(eb2.x, ea.x, 0x07060302u);
            const unsigned E2 = __builtin_amdgcn_perm(eb2.y, ea.y, 0x05040100u);
            const unsigned E3 = __builtin_amdgcn_perm(eb2.y, ea.y, 0x07060302u);
            const unsigned XA = __builtin_amdgcn_perm(xb.u, xa.u, 0x05040100u);
            const unsigned XB = __builtin_amdgcn_perm(xb.u, xa.u, 0x07060302u);
            const half2v f0 = h2cast(E0), f1 = h2cast(E1);
            const half2v f2 = h2cast(E2), f3 = h2cast(E3);
            const half2v va = h2cast(XA), vb = h2cast(XB);
            za[0] = DOT2(f0, va, za[0]); za[1] = DOT2(f1, va, za[1]);
            za[2] = DOT2(f2, va, za[2]); za[3] = DOT2(f3, va, za[3]);
            zb[0] = DOT2(f0, vb, zb[0]); zb[1] = DOT2(f1, vb, zb[1]);
            zb[2] = DOT2(f2, vb, zb[2]); zb[3] = DOT2(f3, vb, zb[3]);
            dd[0] = DOT2(f0, one2, dd[0]); dd[1] = DOT2(f1, one2, dd[1]);
            dd[2] = DOT2(f2, one2, dd[2]); dd[3] = DOT2(f3, one2, dd[3]);
        }
    };

    Grp cur, nxt, remb;
    stage_group(0, 0, cur);

#pragma unroll
    for (int r = 0; r < 4; ++r) {
        const bool rem = degc[r] > 8;                  // wave-uniform branch
        if (rem) stage_group(r, 8, remb);              // hide remainder latency
        if (r < 3) stage_group(r + 1, 0, nxt);         // prefetch next node

#pragma unroll
        for (int h = 0; h < 4; ++h) { za[h] = 0.f; zb[h] = 0.f; dd[h] = 0.f; }

        consume_group(cur);
        if (rem) {
            consume_group(remb);
            for (int s = 16; s < degc[r]; s += 8) {    // deg>16: ~1% of nodes
                Grp tg;
                stage_group(r, s, tg);
                consume_group(tg);
            }
        }

        // combine the two edge-halves
#pragma unroll
        for (int h = 0; h < 4; ++h) {
            dd[h] += __shfl_xor(dd[h], 32, 64);
            za[h] += __shfl_xor(za[h], 32, 64);
            zb[h] += __shfl_xor(zb[h], 32, 64);
        }
        const float r0 = __builtin_amdgcn_rcpf(dd[0] + 1e-9f);
        const float r1 = __builtin_amdgcn_rcpf(dd[1] + 1e-9f);
        const float r2 = __builtin_amdgcn_rcpf(dd[2] + 1e-9f);
        const float r3 = __builtin_amdgcn_rcpf(dd[3] + 1e-9f);
        if (side == 0) {
            half8v o;
            o[0] = (_Float16)(za[0] * r0); o[1] = (_Float16)(za[1] * r1);
            o[2] = (_Float16)(za[2] * r2); o[3] = (_Float16)(za[3] * r3);
            o[4] = (_Float16)(zb[0] * r0); o[5] = (_Float16)(zb[1] * r1);
            o[6] = (_Float16)(zb[2] * r2); o[7] = (_Float16)(zb[3] * r3);
            *(half8v*)(znsh + (wv * 4 + r) * ZSTRIDE + p * 8) = o;
        }
        cur = nxt;
    }
    __syncthreads();

    // ---- Phase B: MFMA col-tile wv; 2 independent 4-chains ----
    const int mrow = l & 15, quad = l >> 4;
    half8v A[8];
    const _Float16* zr = znsh + mrow * ZSTRIDE + quad * 8;
#pragma unroll
    for (int s = 0; s < 8; ++s)
        A[s] = *(const half8v*)(zr + 32 * s);

    const _Float16* gp = G2T + (size_t)(wv * 16 + mrow) * HD + quad * 8;
    f32x4 c0 = {0.f, 0.f, 0.f, 0.f}, c1 = {0.f, 0.f, 0.f, 0.f};
#pragma unroll
    for (int s = 0; s < 4; ++s)
        c0 = __builtin_amdgcn_mfma_f32_16x16x32_f16(A[s], *(const half8v*)(gp + 32 * s), c0, 0, 0, 0);
#pragma unroll
    for (int s = 4; s < 8; ++s)
        c1 = __builtin_amdgcn_mfma_f32_16x16x32_f16(A[s], *(const half8v*)(gp + 32 * s), c1, 0, 0, 0);
    const f32x4 c = c0 + c1;

    const int col = wv * 16 + mrow;
    const float bo = b_out[col];
#pragma unroll
    for (int rho = 0; rho < 4; ++rho) {
        const int nl = quad * 4 + rho;
        const float o = c[rho] + bo;
        const float eo = o > 0.f ? o : expm1f(o);       // ELU(alpha=1)
        ysh[nl][col] = eo + (float)x16[(size_t)(n0 + nl) * DIM + col];
    }
    __syncthreads();

    // ---- epilogue: node-PARALLEL LN; 16-lane group g owns node wv*4+g ----
    {
        const int g = l >> 4, c4 = (l & 15) * 4;
        const int nl = wv * 4 + g;
        const float4 yv = *(const float4*)(&ysh[nl][c4]);
        float s1 = (yv.x + yv.y) + (yv.z + yv.w);
        float s2 = fmaf(yv.x, yv.x, fmaf(yv.y, yv.y, fmaf(yv.z, yv.z, yv.w * yv.w)));
#pragma unroll
        for (int off = 8; off > 0; off >>= 1) {
            s1 += __shfl_xor(s1, off, 64);
            s2 += __shfl_xor(s2, off, 64);
        }
        const float mu = s1 * (1.f / 64.f);
        const float var = fmaf(-mu, mu, s2 * (1.f / 64.f));
        const float rr = rsqrtf(var + 1e-5f);
        const float4 gv = *(const float4*)(ln_g + c4);
        const float4 bv = *(const float4*)(ln_b + c4);
        float4 ov;
        ov.x = (yv.x - mu) * rr * gv.x + bv.x;
        ov.y = (yv.y - mu) * rr * gv.y + bv.y;
        ov.z = (yv.z - mu) * rr * gv.z + bv.z;
        ov.w = (yv.w - mu) * rr * gv.w + bv.w;
        *(float4*)(out + (size_t)(n0 + nl) * DIM + c4) = ov;
    }
}

// ---------------------------------------------------------------------------
extern "C" void kernel_launch(void* const* d_in, const int* in_sizes, int n_in,
                              void* d_out, int out_size, void* d_ws, size_t ws_size,
                              hipStream_t stream)
{
    const float* x        = (const float*)d_in[0];
    const int*   ei       = (const int*)d_in[1];
    const float* W_lin    = (const float*)d_in[2];
    const float* attn_src = (const float*)d_in[3];
    const float* attn_dst = (const float*)d_in[4];
    const float* W_out    = (const float*)d_in[5];
    const float* b_out    = (const float*)d_in[6];
    const float* ln_g     = (const float*)d_in[7];
    const float* ln_b     = (const float*)d_in[8];
    float* out = (float*)d_out;

    // Workspace (~15 MB used; harness poisons full alloc regardless):
    //   x16 6.4MB | S 1.6MB | G2T 32KB | cnt 0.2MB | bucketJ 6.4MB
    char* ws = (char*)d_ws;
    _Float16* x16    = (_Float16*)ws;
    float*    S      = (float*)(x16 + (size_t)N_NODES * DIM);
    _Float16* G2T    = (_Float16*)(S + (size_t)N_NODES * 8);
    int*      cnt    = (int*)(G2T + 64 * HD);
    int*      bucketJ= cnt + N_NODES;

    hipMemsetAsync(cnt, 0, (size_t)N_NODES * sizeof(int), stream);

    k_prep<<<NPREP, 256, 0, stream>>>(x, W_lin, attn_src, attn_dst, W_out, ei,
                                      G2T, x16, S, cnt, bucketJ);

    k_ga<<<N_NODES / 16, 256, 0, stream>>>(cnt, bucketJ, S, x16, G2T,
                                           b_out, ln_g, ln_b, out);
}